// Round 8
// baseline (412.734 us; speedup 1.0000x reference)
//
#include <hip/hip_runtime.h>

#define NETS 32
#define BATCH 4096
#define D0 256
#define D1 512
#define D2 512
#define D3 128
#define MT 128           // batch rows per block (B-stream reuse: block reads net weights ONCE)
#define LDA (D0 + 8)     // 264 halves -> X staging stride
#define LDH (D1 + 8)     // 520 halves -> H staging stride
#define LDO 132          // fp32 epilogue staging stride

using half8 = __attribute__((ext_vector_type(8))) _Float16;
using half4 = __attribute__((ext_vector_type(4))) _Float16;
using f32x4 = __attribute__((ext_vector_type(4))) float;

#define W1_N (NETS * D1 * D0)   // 4,194,304
#define W2_N (NETS * D2 * D1)   // 8,388,608
#define W3_N (NETS * D3 * D2)   // 2,097,152

// ---------------- pure streaming fp32 -> fp16 cast ----------------
// No swizzle: mlp reads W row-major directly (fragment content is identical,
// just gathered per-lane). cvt is now perfectly coalesced both sides:
// 32 B read / 16 B write per thread, contiguous.
__global__ __launch_bounds__(256) void cvt_weights(
    const float* __restrict__ W1, const float* __restrict__ W2,
    const float* __restrict__ W3,
    _Float16* __restrict__ W1h, _Float16* __restrict__ W2h,
    _Float16* __restrict__ W3h) {
    const int i = blockIdx.x * blockDim.x + threadIdx.x;   // one 8-elem chunk per thread
    constexpr int T1 = W1_N / 8, T2 = W2_N / 8;
    const float* src;
    _Float16* dst;
    if (i < T1)           { src = W1 + (size_t)i * 8;            dst = W1h + (size_t)i * 8; }
    else if (i < T1 + T2) { size_t u = (size_t)(i - T1) * 8;      src = W2 + u; dst = W2h + u; }
    else                  { size_t u = (size_t)(i - T1 - T2) * 8; src = W3 + u; dst = W3h + u; }
    f32x4 v0 = *reinterpret_cast<const f32x4*>(src);
    f32x4 v1 = *reinterpret_cast<const f32x4*>(src + 4);
    half8 o;
    o[0] = (_Float16)v0[0]; o[1] = (_Float16)v0[1]; o[2] = (_Float16)v0[2]; o[3] = (_Float16)v0[3];
    o[4] = (_Float16)v1[0]; o[5] = (_Float16)v1[1]; o[6] = (_Float16)v1[2]; o[7] = (_Float16)v1[3];
    *reinterpret_cast<half8*>(dst) = o;
}

// ---------------- software-pipelined layer, row-major B stream ----------------
// wlane = Wnet + (n0 + lane16)*K + quad*8 (halves). Fragment (kk,ni) at
// wlane + ni*16*K + kk*32: lane holds W[n0+ni*16+lane16][kk*32+quad*8..+8]
// == the old swizzled fragment content, byte-identical per lane.
// B double-buffer depth G=2 (= NI): prefetch distance G*MI = 16 MFMA ~ 310 cy.
// Register budget at 4 waves/SIMD (128/wave): acc 64 + a 32 + b 16 + addr ~14.
// (R7 lesson: G=4 here spills -> symmetric FETCH/WRITE inflation.)
template<int K, int NI, int G, int MI>
__device__ __forceinline__ void layer_mfma(const _Float16* As, int lda,
                                           const _Float16* __restrict__ wlane,
                                           int lane16, int quad,
                                           f32x4 (&acc)[MI][NI]) {
    constexpr int KK = K / 32;
    constexpr int NFR = KK * NI;
    constexpr int STEPS = NFR / G;
    static_assert(G <= NI || NI == 1, "step must stay within one kk");
    half8 bcur[G], bnxt[G];
    half8 a[MI];
#pragma unroll
    for (int g = 0; g < G; ++g) {
        const int kk = g / NI, ni = g % NI;
        bcur[g] = *reinterpret_cast<const half8*>(wlane + (size_t)ni * 16 * K + kk * 32);
    }
#pragma unroll
    for (int s = 0; s < STEPS; ++s) {
        const int fb = s * G;
        if (s + 1 < STEPS) {
#pragma unroll
            for (int g = 0; g < G; ++g) {
                const int f = fb + G + g;
                const int kk = f / NI, ni = f % NI;
                bnxt[g] = *reinterpret_cast<const half8*>(wlane + (size_t)ni * 16 * K + kk * 32);
            }
        }
        if (fb % NI == 0) {
            const int kk = fb / NI;
#pragma unroll
            for (int mi = 0; mi < MI; ++mi)
                a[mi] = *reinterpret_cast<const half8*>(
                    As + (mi * 16 + lane16) * lda + kk * 32 + quad * 8);
        }
#pragma unroll
        for (int g = 0; g < G; ++g) {
            const int ni = (fb + g) % NI;
#pragma unroll
            for (int mi = 0; mi < MI; ++mi)
                acc[mi][ni] = __builtin_amdgcn_mfma_f32_16x16x32_f16(a[mi], bcur[g], acc[mi][ni], 0, 0, 0);
        }
        if (s + 1 < STEPS) {
#pragma unroll
            for (int g = 0; g < G; ++g) bcur[g] = bnxt[g];
        }
    }
}

template<int MI, int NI>
__device__ __forceinline__ void store_act(f32x4 (&acc)[MI][NI], const float* __restrict__ bias,
                                          _Float16* dst, int ldd, int n_base,
                                          int lane16, int quad) {
#pragma unroll
    for (int ni = 0; ni < NI; ++ni) {
        float bv = bias[n_base + ni * 16 + lane16];
        int col = n_base + ni * 16 + lane16;
#pragma unroll
        for (int mi = 0; mi < MI; ++mi) {
#pragma unroll
            for (int r = 0; r < 4; ++r) {
                float v = acc[mi][ni][r] + bv;
                v = fmaxf(v, 0.0f);                        // relu
                int row = mi * 16 + quad * 4 + r;
                dst[row * ldd + col] = (_Float16)v;
            }
        }
    }
}

// ---------------- fused 3-layer MLP: 128-row tile, 16 waves, 1 block/CU ----------------
// Wave owns 128 rows x 32 cols (acc[8][2]=64 AGPR) -> the block's 16 waves
// cover 512 cols with NO row-split: each B fragment is read by exactly ONE
// wave -> block reads net weights once (1.8 MB). L2 B-traffic drops
// 3.67 GB -> 1.07 GB: arithmetic intensity 112 FLOP/B vs 72 balance ->
// no longer L2-BW-bound (the R0..R7 ~41% MfmaUtil wall).
// LDS 133 KB -> 1 block/CU; 16 waves = 4 waves/SIMD (TLP latency cover).
__global__ __launch_bounds__(1024, 4) void mlp_fused(
    const float* __restrict__ X,
    const _Float16* __restrict__ W1h, const float* __restrict__ b1,
    const _Float16* __restrict__ W2h, const float* __restrict__ b2,
    const _Float16* __restrict__ W3h, const float* __restrict__ b3,
    float* __restrict__ out) {
    __shared__ __align__(16) _Float16 buf[MT * LDH];   // X (LDA) -> H1/H2 (LDH) -> fp32 out stage

    const int tid = threadIdx.x;
    const int w = tid >> 6;               // 0..15
    const int l = tid & 63;
    const int lane16 = l & 15;
    const int quad = l >> 4;

    // XCD-locality: 1024 blocks; per XCD-round all 32 CUs run the SAME net
    // (1.8 MB fp16 weights L2-resident, reused by every CU).
    const int bb = blockIdx.x;            // 0..1023
    const int xcd = bb & 7;
    const int s = bb >> 3;                // 0..127
    const int net = xcd * 4 + (s >> 5);   // 0..31
    const int mt = s & 31;                // 0..31
    const int m0 = mt * MT;

    // ---- stage X tile [MT][D0] fp32 -> fp16 into buf (LDA layout) ----
    // MT*D0/4 = 8192 float4 chunks; 1024 threads x 8 iters.
    {
        const float* xsrc = X + (size_t)m0 * D0;
#pragma unroll
        for (int it = 0; it < 8; ++it) {
            int chunk = it * 1024 + tid;  // 0..8191; 64 float4 per row
            int row = chunk >> 6;
            int c4 = chunk & 63;
            float4 v = *reinterpret_cast<const float4*>(xsrc + row * D0 + c4 * 4);
            half4 o;
            o[0] = (_Float16)v.x; o[1] = (_Float16)v.y;
            o[2] = (_Float16)v.z; o[3] = (_Float16)v.w;
            *reinterpret_cast<half4*>(&buf[row * LDA + c4 * 4]) = o;
        }
    }
    __syncthreads();

    // ---- layer 1: H1 = relu(X @ W1^T + b1), K=256 (wave: 128 rows x 32 cols) ----
    {
        f32x4 acc[8][2] = {};
        const _Float16* wlane = W1h + (size_t)net * D1 * D0 + (size_t)(w * 32 + lane16) * D0 + quad * 8;
        layer_mfma<D0, 2, 2, 8>(buf, LDA, wlane, lane16, quad, acc);
        __syncthreads();                               // all X reads done
        store_act<8, 2>(acc, b1 + net * D1, buf, LDH, w * 32, lane16, quad);
    }
    __syncthreads();

    // ---- layer 2: H2 = relu(H1 @ W2^T + b2), K=512 ----
    {
        f32x4 acc[8][2] = {};
        const _Float16* wlane = W2h + (size_t)net * D2 * D1 + (size_t)(w * 32 + lane16) * D1 + quad * 8;
        layer_mfma<D1, 2, 2, 8>(buf, LDH, wlane, lane16, quad, acc);
        __syncthreads();                               // all H1 reads done
        store_act<8, 2>(acc, b2 + net * D2, buf, LDH, w * 32, lane16, quad);
    }
    __syncthreads();

    // ---- layer 3: out = H2 @ W3^T + b3, K=512, N=128 ----
    // 16 waves: wr = w>>3 picks row half (64 rows), wc = w&7 picks 16 cols.
    // Staged epilogue: acc -> LDS fp32 -> cooperative FULL-LINE float4 writes
    // (32 lanes x 16 B = 512 contiguous B per out row).
    {
        const int wr = w >> 3, wc = w & 7;
        f32x4 acc[4][1] = {};
        const _Float16* wlane = W3h + (size_t)net * D3 * D2 + (size_t)(wc * 16 + lane16) * D2 + quad * 8;
        layer_mfma<D2, 1, 1, 4>(buf + wr * 64 * LDH, LDH, wlane, lane16, quad, acc);
        __syncthreads();                               // all H2 reads done
        float* buff = reinterpret_cast<float*>(buf);   // reuse as [128][LDO] fp32
        const int n0 = wc * 16;
        const float bv = b3[net * D3 + n0 + lane16];
#pragma unroll
        for (int mi = 0; mi < 4; ++mi) {
#pragma unroll
            for (int r = 0; r < 4; ++r) {
                int row = wr * 64 + mi * 16 + quad * 4 + r;
                buff[row * LDO + n0 + lane16] = acc[mi][0][r] + bv;
            }
        }
        __syncthreads();
        // 128 rows x 128 floats = 4096 float4; 1024 threads x 4.
#pragma unroll
        for (int it = 0; it < 4; ++it) {
            int idx = it * 1024 + tid;                 // 32 float4 per row
            int row = idx >> 5;
            int c4 = idx & 31;
            f32x4 v = *reinterpret_cast<const f32x4*>(&buff[row * LDO + c4 * 4]);
            *reinterpret_cast<f32x4*>(
                &out[(size_t)(m0 + row) * (NETS * D3) + net * D3 + c4 * 4]) = v;
        }
    }
}

extern "C" void kernel_launch(void* const* d_in, const int* in_sizes, int n_in,
                              void* d_out, int out_size, void* d_ws, size_t ws_size,
                              hipStream_t stream) {
    const float* x  = (const float*)d_in[0];
    const float* W1 = (const float*)d_in[1];
    const float* b1 = (const float*)d_in[2];
    const float* W2 = (const float*)d_in[3];
    const float* b2 = (const float*)d_in[4];
    const float* W3 = (const float*)d_in[5];
    const float* b3 = (const float*)d_in[6];
    float* out = (float*)d_out;

    // ws layout (fp16, row-major): W1h | W2h | W3h = ~29.4 MB
    _Float16* W1h = (_Float16*)d_ws;
    _Float16* W2h = W1h + (size_t)W1_N;
    _Float16* W3h = W2h + (size_t)W2_N;

    const int totalT = (W1_N + W2_N + W3_N) / 8;       // 1,835,008 threads
    cvt_weights<<<totalT / 256, 256, 0, stream>>>(W1, W2, W3, W1h, W2h, W3h);

    mlp_fused<<<NETS * (BATCH / MT), 1024, 0, stream>>>(x, W1h, b1, W2h, b2, W3h, b3, out);
}